// Round 1
// baseline (212.893 us; speedup 1.0000x reference)
//
#include <hip/hip_runtime.h>
#include <hip/hip_bf16.h>

// Problem constants (reference: N=2048, F=128, HEADS=8, OUT_DIM=8, ALPHA=0.2)
#define NN      2048
#define FDIM    128
#define HEADS   8
#define ODIM    8
#define HID     64      // HEADS*ODIM
#define ALPHA   0.2f
#define TB      512     // threads per block in attention kernel
#define JPT     4       // j's per thread = NN/TB

__device__ __forceinline__ float lrelu(float x) {
    return x > 0.f ? x : ALPHA * x;
}

// ---------------------------------------------------------------------------
// Kernel 1: h = X @ W  (per-node row), s1 = h . a1, s2 = h . a2  (per head)
// grid = NN blocks, block = 64 threads (1 wave)
// ---------------------------------------------------------------------------
__global__ __launch_bounds__(64) void gat_prep(
        const float* __restrict__ X,   // (NN, FDIM)
        const float* __restrict__ W,   // (FDIM, HID)
        const float* __restrict__ ak,  // (2*ODIM,)
        float* __restrict__ H,         // (NN, HID)
        float* __restrict__ S1,        // (NN, HEADS)
        float* __restrict__ S2) {      // (NN, HEADS)
    const int n = blockIdx.x;
    const int t = threadIdx.x;

    __shared__ float Xs[FDIM];
    __shared__ float hs[HID];

    Xs[t]      = X[(size_t)n * FDIM + t];
    Xs[t + 64] = X[(size_t)n * FDIM + 64 + t];
    __syncthreads();

    float acc = 0.f;
    #pragma unroll 8
    for (int k = 0; k < FDIM; ++k)
        acc = fmaf(Xs[k], W[k * HID + t], acc);   // Xs[k]: LDS broadcast; W col: coalesced

    H[(size_t)n * HID + t] = acc;
    hs[t] = acc;
    __syncthreads();

    if (t < 16) {
        const int head = t & 7;
        const float* a = ak + ((t < 8) ? 0 : ODIM);
        float s = 0.f;
        #pragma unroll
        for (int d = 0; d < ODIM; ++d)
            s = fmaf(hs[head * ODIM + d], a[d], s);
        if (t < 8) S1[n * HEADS + head] = s;
        else       S2[n * HEADS + head] = s;
    }
}

// ---------------------------------------------------------------------------
// Kernel 2: per row i — masked leaky-relu scores, softmax over j per head,
// out[i,j,d] = lrelu( sum_h attn[i,j,h] * h[i,h,d] )
// grid = NN blocks (one per i), block = TB threads (8 waves)
// ---------------------------------------------------------------------------
__global__ __launch_bounds__(TB) void gat_attn(
        const int*   __restrict__ A,    // (NN, NN)
        const float* __restrict__ H,    // (NN, HID)
        const float* __restrict__ S1,   // (NN, HEADS)
        const float* __restrict__ S2,   // (NN, HEADS)
        float* __restrict__ out) {      // (NN, NN, ODIM)
    const int i    = blockIdx.x;
    const int t    = threadIdx.x;
    const int wave = t >> 6;
    const int lane = t & 63;

    __shared__ int   As[NN];            // 8 KB: adjacency row
    __shared__ float redM[8 * HEADS];   // cross-wave max reduction
    __shared__ float redL[8 * HEADS];   // cross-wave sum reduction
    __shared__ float hhS[HID];          // h[i,h,d] / l[h]

    // --- load A row (coalesced int4) ---
    const int4* Arow4 = (const int4*)(A + (size_t)i * NN);
    ((int4*)As)[t] = Arow4[t];

    // --- s1 row (broadcast, L1-hit) ---
    float s1r[HEADS];
    #pragma unroll
    for (int h = 0; h < HEADS; ++h) s1r[h] = S1[i * HEADS + h];

    __syncthreads();

    // --- pass 1: e into registers, per-thread max per head ---
    float ev[JPT][HEADS];
    float mloc[HEADS];
    #pragma unroll
    for (int h = 0; h < HEADS; ++h) mloc[h] = -3.0e38f;

    #pragma unroll
    for (int jj = 0; jj < JPT; ++jj) {
        const int j = t + jj * TB;
        const float4 s2a = *(const float4*)(S2 + j * HEADS);
        const float4 s2b = *(const float4*)(S2 + j * HEADS + 4);
        const bool msk = As[j] > 0;
        const float s2v[8] = {s2a.x, s2a.y, s2a.z, s2a.w,
                              s2b.x, s2b.y, s2b.z, s2b.w};
        #pragma unroll
        for (int h = 0; h < HEADS; ++h) {
            const float x = s1r[h] + s2v[h];
            const float e = msk ? lrelu(x) : -1.0e9f;
            ev[jj][h] = e;
            mloc[h] = fmaxf(mloc[h], e);
        }
    }

    // --- block max per head: wave butterfly, then cross-wave via LDS ---
    #pragma unroll
    for (int h = 0; h < HEADS; ++h) {
        float v = mloc[h];
        #pragma unroll
        for (int off = 32; off; off >>= 1)
            v = fmaxf(v, __shfl_xor(v, off));
        if (lane == 0) redM[wave * HEADS + h] = v;
    }
    __syncthreads();
    float mf[HEADS];
    #pragma unroll
    for (int h = 0; h < HEADS; ++h) {
        float v = redM[h];
        #pragma unroll
        for (int w = 1; w < 8; ++w)
            v = fmaxf(v, redM[w * HEADS + h]);   // LDS broadcast reads
        mf[h] = v;
    }

    // --- pass 2: p = exp(e - m) in place, per-thread sums ---
    float ls[HEADS];
    #pragma unroll
    for (int h = 0; h < HEADS; ++h) ls[h] = 0.f;
    #pragma unroll
    for (int jj = 0; jj < JPT; ++jj) {
        #pragma unroll
        for (int h = 0; h < HEADS; ++h) {
            const float p = __expf(ev[jj][h] - mf[h]);
            ev[jj][h] = p;
            ls[h] += p;
        }
    }

    // --- block sum per head ---
    #pragma unroll
    for (int h = 0; h < HEADS; ++h) {
        float v = ls[h];
        #pragma unroll
        for (int off = 32; off; off >>= 1)
            v += __shfl_xor(v, off);
        if (lane == 0) redL[wave * HEADS + h] = v;
    }
    __syncthreads();
    float lf[HEADS];
    #pragma unroll
    for (int h = 0; h < HEADS; ++h) {
        float v = redL[h];
        #pragma unroll
        for (int w = 1; w < 8; ++w)
            v += redL[w * HEADS + h];
        lf[h] = v;
    }

    // --- hh[h*8+d] = h[i,h,d] / l[h]  (normalization folded into h) ---
    if (t < HID)
        hhS[t] = H[(size_t)i * HID + t] / lf[t >> 3];
    __syncthreads();

    // --- pass 3: out[j,d] = lrelu( sum_h p[j,h] * hh[h,d] ) ---
    float oacc[JPT][ODIM];
    #pragma unroll
    for (int jj = 0; jj < JPT; ++jj)
        #pragma unroll
        for (int d = 0; d < ODIM; ++d)
            oacc[jj][d] = 0.f;

    #pragma unroll
    for (int h = 0; h < HEADS; ++h) {
        const float4 h0 = *(const float4*)(hhS + h * ODIM);      // broadcast
        const float4 h1 = *(const float4*)(hhS + h * ODIM + 4);  // broadcast
        #pragma unroll
        for (int jj = 0; jj < JPT; ++jj) {
            const float p = ev[jj][h];
            oacc[jj][0] = fmaf(p, h0.x, oacc[jj][0]);
            oacc[jj][1] = fmaf(p, h0.y, oacc[jj][1]);
            oacc[jj][2] = fmaf(p, h0.z, oacc[jj][2]);
            oacc[jj][3] = fmaf(p, h0.w, oacc[jj][3]);
            oacc[jj][4] = fmaf(p, h1.x, oacc[jj][4]);
            oacc[jj][5] = fmaf(p, h1.y, oacc[jj][5]);
            oacc[jj][6] = fmaf(p, h1.z, oacc[jj][6]);
            oacc[jj][7] = fmaf(p, h1.w, oacc[jj][7]);
        }
    }

    #pragma unroll
    for (int jj = 0; jj < JPT; ++jj) {
        const int j = t + jj * TB;
        const size_t base = ((size_t)i * NN + j) * ODIM;
        float4 o0, o1;
        o0.x = lrelu(oacc[jj][0]); o0.y = lrelu(oacc[jj][1]);
        o0.z = lrelu(oacc[jj][2]); o0.w = lrelu(oacc[jj][3]);
        o1.x = lrelu(oacc[jj][4]); o1.y = lrelu(oacc[jj][5]);
        o1.z = lrelu(oacc[jj][6]); o1.w = lrelu(oacc[jj][7]);
        *(float4*)(out + base)     = o0;   // coalesced: 32 B/lane contiguous
        *(float4*)(out + base + 4) = o1;
    }
}

// ---------------------------------------------------------------------------
extern "C" void kernel_launch(void* const* d_in, const int* in_sizes, int n_in,
                              void* d_out, int out_size, void* d_ws, size_t ws_size,
                              hipStream_t stream) {
    const float* X  = (const float*)d_in[0];   // (2048,128) fp32
    const int*   A  = (const int*)  d_in[1];   // (2048,2048) int32
    const float* W  = (const float*)d_in[2];   // (128,64) fp32
    const float* ak = (const float*)d_in[3];   // (16,1) fp32
    float* out = (float*)d_out;                // (2048*2048*8) fp32

    // workspace layout: H (2048*64) | S1 (2048*8) | S2 (2048*8)  = 640 KB
    float* H  = (float*)d_ws;
    float* S1 = H  + (size_t)NN * HID;
    float* S2 = S1 + (size_t)NN * HEADS;

    gat_prep<<<NN, 64, 0, stream>>>(X, W, ak, H, S1, S2);
    gat_attn<<<NN, TB, 0, stream>>>(A, H, S1, S2, out);
}

// Round 2
// 178.991 us; speedup vs baseline: 1.1894x; 1.1894x over previous
//
#include <hip/hip_runtime.h>
#include <hip/hip_bf16.h>

// Problem constants (reference: N=2048, F=128, HEADS=8, OUT_DIM=8, ALPHA=0.2)
#define NN      2048
#define FDIM    128
#define HEADS   8
#define ODIM    8
#define HID     64      // HEADS*ODIM
#define ALPHA   0.2f

__device__ __forceinline__ float lrelu(float x) {
    return x > 0.f ? x : ALPHA * x;
}

// ---------------------------------------------------------------------------
// Kernel 1: h = X @ W  (per-node row), s1 = h . a1, s2 = h . a2  (per head)
// grid = NN blocks, block = 64 threads (1 wave)
// ---------------------------------------------------------------------------
__global__ __launch_bounds__(64) void gat_prep(
        const float* __restrict__ X,   // (NN, FDIM)
        const float* __restrict__ W,   // (FDIM, HID)
        const float* __restrict__ ak,  // (2*ODIM,)
        float* __restrict__ H,         // (NN, HID)
        float* __restrict__ S1,        // (NN, HEADS)
        float* __restrict__ S2) {      // (NN, HEADS)
    const int n = blockIdx.x;
    const int t = threadIdx.x;

    __shared__ float Xs[FDIM];
    __shared__ float hs[HID];

    Xs[t]      = X[(size_t)n * FDIM + t];
    Xs[t + 64] = X[(size_t)n * FDIM + 64 + t];
    __syncthreads();

    float acc = 0.f;
    #pragma unroll 8
    for (int k = 0; k < FDIM; ++k)
        acc = fmaf(Xs[k], W[k * HID + t], acc);   // Xs[k]: LDS broadcast; W col: coalesced

    H[(size_t)n * HID + t] = acc;
    hs[t] = acc;
    __syncthreads();

    if (t < 16) {
        const int head = t & 7;
        const float* a = ak + ((t < 8) ? 0 : ODIM);
        float s = 0.f;
        #pragma unroll
        for (int d = 0; d < ODIM; ++d)
            s = fmaf(hs[head * ODIM + d], a[d], s);
        if (t < 8) S1[n * HEADS + head] = s;
        else       S2[n * HEADS + head] = s;
    }
}

// ---------------------------------------------------------------------------
// Kernel 2: per row i — LF[i,h] = sum_j mask(i,j) * exp(lrelu(s1[i,h]+s2[j,h]))
// Max-free softmax denominator: scores are O(1), masked lanes contribute 0
// (exactly matching reference's exp(-1e9 - m) == 0 in fp32).
// grid = NN blocks, block = 512 (8 waves), 4 j per thread
// ---------------------------------------------------------------------------
__global__ __launch_bounds__(512) void gat_rowsum(
        const int*   __restrict__ A,    // (NN, NN)
        const float* __restrict__ S1,   // (NN, HEADS)
        const float* __restrict__ S2,   // (NN, HEADS)
        float* __restrict__ LF) {       // (NN, HEADS)
    const int i    = blockIdx.x;
    const int t    = threadIdx.x;
    const int wave = t >> 6;
    const int lane = t & 63;

    __shared__ int   As[NN];           // 8 KB adjacency row
    __shared__ float redL[8 * HEADS];

    const int4* Arow4 = (const int4*)(A + (size_t)i * NN);
    ((int4*)As)[t] = Arow4[t];         // 512 * int4 = 2048 ints

    float s1r[HEADS];
    #pragma unroll
    for (int h = 0; h < HEADS; ++h) s1r[h] = S1[i * HEADS + h];

    __syncthreads();

    float ls[HEADS];
    #pragma unroll
    for (int h = 0; h < HEADS; ++h) ls[h] = 0.f;

    #pragma unroll
    for (int jj = 0; jj < 4; ++jj) {
        const int j = t + jj * 512;
        const float4 s2a = *(const float4*)(S2 + j * HEADS);
        const float4 s2b = *(const float4*)(S2 + j * HEADS + 4);
        const bool msk = As[j] > 0;
        const float s2v[8] = {s2a.x, s2a.y, s2a.z, s2a.w,
                              s2b.x, s2b.y, s2b.z, s2b.w};
        #pragma unroll
        for (int h = 0; h < HEADS; ++h) {
            const float x = s1r[h] + s2v[h];
            ls[h] += msk ? __expf(lrelu(x)) : 0.f;
        }
    }

    #pragma unroll
    for (int h = 0; h < HEADS; ++h) {
        float v = ls[h];
        #pragma unroll
        for (int off = 32; off; off >>= 1)
            v += __shfl_xor(v, off);
        if (lane == 0) redL[wave * HEADS + h] = v;
    }
    __syncthreads();

    if (t < HEADS) {
        float v = 0.f;
        #pragma unroll
        for (int w = 0; w < 8; ++w)
            v += redL[w * HEADS + t];
        LF[i * HEADS + t] = v;
    }
}

// ---------------------------------------------------------------------------
// Kernel 3: pure write stream. Per row i, recompute p = exp(e) and emit
// out[i,j,d] = lrelu( sum_h p[j,h] * h[i,h,d] / LF[i,h] ).
// hh held in 64 registers (no LDS in the hot loop); ONE barrier total.
// grid = NN blocks, block = 256 (4 waves), 8 j per thread
// ---------------------------------------------------------------------------
__global__ __launch_bounds__(256, 4) void gat_write(
        const int*   __restrict__ A,    // (NN, NN)
        const float* __restrict__ H,    // (NN, HID)
        const float* __restrict__ S1,   // (NN, HEADS)
        const float* __restrict__ S2,   // (NN, HEADS)
        const float* __restrict__ LF,   // (NN, HEADS)
        float* __restrict__ out) {      // (NN, NN, ODIM)
    const int i = blockIdx.x;
    const int t = threadIdx.x;

    __shared__ int   As[NN];           // 8 KB adjacency row
    __shared__ float hhS[HID];

    const int4* Arow4 = (const int4*)(A + (size_t)i * NN);
    ((int4*)As)[t]       = Arow4[t];
    ((int4*)As)[t + 256] = Arow4[t + 256];

    if (t < HID)
        hhS[t] = H[(size_t)i * HID + t] / LF[i * HEADS + (t >> 3)];

    float s1r[HEADS];
    #pragma unroll
    for (int h = 0; h < HEADS; ++h) s1r[h] = S1[i * HEADS + h];

    __syncthreads();

    // one-time LDS -> registers (b128 broadcast reads); hot loop is reg-only
    float hh[HID];
    #pragma unroll
    for (int k = 0; k < HID; k += 4) {
        const float4 v = *(const float4*)(hhS + k);
        hh[k] = v.x; hh[k + 1] = v.y; hh[k + 2] = v.z; hh[k + 3] = v.w;
    }

    #pragma unroll
    for (int jj = 0; jj < 8; ++jj) {
        const int j = t + jj * 256;
        const float4 s2a = *(const float4*)(S2 + j * HEADS);
        const float4 s2b = *(const float4*)(S2 + j * HEADS + 4);
        const bool msk = As[j] > 0;
        const float s2v[8] = {s2a.x, s2a.y, s2a.z, s2a.w,
                              s2b.x, s2b.y, s2b.z, s2b.w};

        float p[HEADS];
        #pragma unroll
        for (int h = 0; h < HEADS; ++h) {
            const float x = s1r[h] + s2v[h];
            p[h] = msk ? __expf(lrelu(x)) : 0.f;
        }

        float o[ODIM];
        #pragma unroll
        for (int d = 0; d < ODIM; ++d) o[d] = 0.f;
        #pragma unroll
        for (int h = 0; h < HEADS; ++h) {
            #pragma unroll
            for (int d = 0; d < ODIM; ++d)
                o[d] = fmaf(p[h], hh[h * ODIM + d], o[d]);
        }

        const size_t base = ((size_t)i * NN + j) * ODIM;
        float4 o0, o1;
        o0.x = lrelu(o[0]); o0.y = lrelu(o[1]);
        o0.z = lrelu(o[2]); o0.w = lrelu(o[3]);
        o1.x = lrelu(o[4]); o1.y = lrelu(o[5]);
        o1.z = lrelu(o[6]); o1.w = lrelu(o[7]);
        *(float4*)(out + base)     = o0;   // coalesced 32 B/lane contiguous
        *(float4*)(out + base + 4) = o1;
    }
}

// ---------------------------------------------------------------------------
extern "C" void kernel_launch(void* const* d_in, const int* in_sizes, int n_in,
                              void* d_out, int out_size, void* d_ws, size_t ws_size,
                              hipStream_t stream) {
    const float* X  = (const float*)d_in[0];   // (2048,128) fp32
    const int*   A  = (const int*)  d_in[1];   // (2048,2048) int32
    const float* W  = (const float*)d_in[2];   // (128,64) fp32
    const float* ak = (const float*)d_in[3];   // (16,1) fp32
    float* out = (float*)d_out;                // (2048*2048*8) fp32

    // workspace layout: H (512 KB) | S1 (64 KB) | S2 (64 KB) | LF (64 KB)
    float* H  = (float*)d_ws;
    float* S1 = H  + (size_t)NN * HID;
    float* S2 = S1 + (size_t)NN * HEADS;
    float* LF = S2 + (size_t)NN * HEADS;

    gat_prep  <<<NN,  64, 0, stream>>>(X, W, ak, H, S1, S2);
    gat_rowsum<<<NN, 512, 0, stream>>>(A, S1, S2, LF);
    gat_write <<<NN, 256, 0, stream>>>(A, H, S1, S2, LF, out);
}